// Round 13
// baseline (429.436 us; speedup 1.0000x reference)
//
#include <hip/hip_runtime.h>
#include <hip/hip_bf16.h>

// 6 layers of relu(spmm(graph, x@W+b)), B=256, NN=255 nodes.
// R12 = R11 + BARRIER-FREE phase-1 K-loop:
//   - As replicated per wave (4 x 4KB; lane stages row 'lane') -> no cross-wave
//     A dependence. Bs staging was already wave-local (thread t stages row t,
//     wave w reads rows w*64..+63). Zero s_barrier in the K-loop; per-wave
//     LDS ordering via wave_barrier() fences (R8-proven pattern).
//   - LDS stays 32768 B (16KB As copies + 16KB Bs = Ys overlay) -> 5 blocks/CU.
//   - 2 __syncthreads per block (Ys overlay guard), phase-2 S double-buffer.
//   - scan_k parallelized (Hillis-Steele) replacing 255-iter serial loop.

#define NN 255
#define YCH 2048           // ushorts per Y k-chunk: 64 rows * 32

typedef __attribute__((ext_vector_type(8))) short short8;
typedef __attribute__((ext_vector_type(4))) float floatx4;

__device__ __forceinline__ float bf2f(ushort u) {
    union { uint u; float f; } c; c.u = ((uint)u) << 16; return c.f;
}
__device__ __forceinline__ ushort f2bf(float f) {
    union { float f; uint u; } c; c.f = f;
    uint u = c.u + 0x7fff + ((c.u >> 16) & 1);
    return (ushort)(u >> 16);
}
__device__ __forceinline__ short8 u4_frag(uint4 v) {
    union { uint4 u; short8 s; } c; c.u = v; return c.s;
}

// ---------------- graph preprocessing ----------------
struct Graphs {
    const int*   rows[4];
    const int*   cols[4];
    const float* vals[4];
    int*   cnt[4];
    int*   fill[4];
    int*   rowptr[4];
    int*   csr_col[4];
    float* csr_val[4];
};

__global__ void zero_k(int* p, int n) {
    int i = blockIdx.x * blockDim.x + threadIdx.x;
    if (i < n) p[i] = 0;
}

// per-edge: histogram count + dense-S scatter + rowsum, all atomics
__global__ void edge_k(Graphs g, float* Sd, float* rs, int nnz) {
    int gi = blockIdx.y;
    int e = blockIdx.x * blockDim.x + threadIdx.x;
    if (e < nnz) {
        int r = g.rows[gi][e], c = g.cols[gi][e];
        float v = g.vals[gi][e];
        atomicAdd(&g.cnt[gi][r], 1);
        atomicAdd(&Sd[gi * 65536 + r * 256 + c], v);
        atomicAdd(&rs[gi * 256 + r], v);
    }
}

// parallel exclusive scan over 255 counts -> rowptr[256] (per graph)
__global__ void scan_k(Graphs g) {
    __shared__ int buf[256];
    int gi = blockIdx.x, t = threadIdx.x;
    int v = (t < NN) ? g.cnt[gi][t] : 0;
    buf[t] = v;
    __syncthreads();
    #pragma unroll
    for (int off = 1; off < 256; off <<= 1) {
        int x = (t >= off) ? buf[t - off] : 0;
        __syncthreads();
        buf[t] += x;
        __syncthreads();
    }
    g.rowptr[gi][t] = buf[t] - v;   // exclusive; t=255 gives total (v=0)
}

__global__ void fill_k(Graphs g, int nnz) {
    int gi = blockIdx.y;
    int e = blockIdx.x * blockDim.x + threadIdx.x;
    if (e < nnz) {
        int r = g.rows[gi][e];
        int p = g.rowptr[gi][r] + atomicAdd(&g.fill[gi][r], 1);
        g.csr_col[gi][p] = g.cols[gi][e];
        g.csr_val[gi][p] = g.vals[gi][e];
    }
}

// merged converts: Sd->Sb (bf16) then 4 weight transposes (ladder on idx)
__device__ __forceinline__ void wpiece(const float* __restrict__ W, ushort* __restrict__ Wt,
                                       int K, int N, int Kpad, int idx) {
    int n = idx / Kpad, k = idx - n * Kpad;
    float v = (n < N && k < K) ? W[(size_t)k * N + n] : 0.f;
    Wt[idx] = f2bf(v);
}

__global__ void conv_k(const float* __restrict__ Sd, ushort* __restrict__ Sb,
                       const float* __restrict__ W1, ushort* __restrict__ Wt1,
                       const float* __restrict__ W2, ushort* __restrict__ Wt2,
                       const float* __restrict__ W3, ushort* __restrict__ Wt3,
                       const float* __restrict__ W4, ushort* __restrict__ Wt4) {
    int idx = blockIdx.x * blockDim.x + threadIdx.x;
    if (idx < 262144) { Sb[idx] = f2bf(Sd[idx]); return; }
    idx -= 262144;
    if (idx < 133120) { wpiece(W1, Wt1, 400, 300, 416, idx); return; }
    idx -= 133120;
    if (idx < 40960)  { wpiece(W2, Wt2, 300, 100, 320, idx); return; }
    idx -= 40960;
    if (idx < 40960)  { wpiece(W3, Wt3, 100, 300, 128, idx); return; }
    idx -= 40960;
    if (idx < 143360) { wpiece(W4, Wt4, 300, 400, 320, idx); }
}

// ---------------- L0 spmm: F=2, f32 in (H, compact), f32 out ----------------
__global__ __launch_bounds__(256) void spmm_f2_f32(const float* __restrict__ H,
                                                   float* __restrict__ T,
                                                   const int* __restrict__ rowptr,
                                                   const int* __restrict__ cols,
                                                   const float* __restrict__ vals,
                                                   int total) {
    int tt = blockIdx.x * blockDim.x + threadIdx.x;
    if (tt >= total) return;
    int r = tt % NN, b = tt / NN;
    int s = rowptr[r], e = rowptr[r + 1];
    const float* Hb = H + (size_t)b * NN * 2;
    float a0 = 0.f, a1 = 0.f;
    for (int i = s; i < e; ++i) {
        float v = vals[i]; int c = cols[i];
        a0 = fmaf(v, Hb[c * 2], a0);
        a1 = fmaf(v, Hb[c * 2 + 1], a1);
    }
    T[(size_t)tt * 2] = a0;
    T[(size_t)tt * 2 + 1] = a1;
}

// -------- L0 GEMM (K=2): relu(acc + rs[node]*b[n]) -> N-layout [b*256+node][416] --------
__global__ __launch_bounds__(256) void gemm_k2_relu(const float* __restrict__ T,
                                                    const float* __restrict__ W,
                                                    const float* __restrict__ bias,
                                                    const float* __restrict__ rs,
                                                    ushort* __restrict__ Y,
                                                    int Mp, int N, int Ns) {
    int half = Ns >> 1;    // 208
    int idx = blockIdx.x * blockDim.x + threadIdx.x;
    if (idx >= Mp * half) return;
    int m = idx / half, n2 = (idx - m * half) * 2;
    int node = m & 255, b = m >> 8;
    uint o = 0;
    if (n2 < N && node < NN) {
        int mc = b * NN + node;
        float x0 = T[mc * 2], x1 = T[mc * 2 + 1];
        float rsm = rs[node];
        float y0 = fmaf(x0, W[n2],     fmaf(x1, W[N + n2],     rsm * bias[n2]));
        float y1 = fmaf(x0, W[n2 + 1], fmaf(x1, W[N + n2 + 1], rsm * bias[n2 + 1]));
        o = (uint)f2bf(fmaxf(y0, 0.f)) | ((uint)f2bf(fmaxf(y1, 0.f)) << 16);
    }
    ((uint*)Y)[idx] = o;
}

// =======================================================================
// Fused layer: block = (batch b, 64-feature tile ft).
//   phase 1: Y[64f,256c] = Wt_tile @ X_b^T + bias  (wave-local LDS staging,
//            per-wave As copies, NO barriers in the K-loop)
//   phase 2: Z[256r,64f] = relu(S @ Y)             (S from L2 double-buffered,
//            Y from LDS, no barriers)
// LDS rotation layout: row stride 32 ushorts; 16B granule g of row r at
// position (g + (r>>2))&3 -> all frag ops aligned b128, uniform banks.
// =======================================================================
__global__ __launch_bounds__(256, 3) void fused_layer(const ushort* __restrict__ X,
                                                      const ushort* __restrict__ Wt,
                                                      const ushort* __restrict__ Sg,
                                                      const float* __restrict__ bias,
                                                      ushort* __restrict__ Z,
                                                      int Kpad, int Nfeat, int FsN,
                                                      int nft) {
    __shared__ ushort smem[8 * YCH];     // 32768 B total -> 5 blocks/CU
    ushort* Ys = smem;                   // overlay: 8 chunks of [64][32]

    int li = blockIdx.x;
    int x = li & 7, rr = li >> 3;
    int ft = rr % nft, b = (rr / nft) * 8 + x;
    int f0 = ft * 64;

    int t = threadIdx.x;
    int w = t >> 6, lane = t & 63;
    int frow = lane & 15, quad = lane >> 4;
    int rot = ((quad + (frow >> 2)) & 3) * 8;   // frag-read granule offset (ushorts)

    // ---------------- phase 1: barrier-free K-loop ----------------
    ushort* Asw = smem + w * 2048;       // this wave's As copy [64][32] (4KB)
    ushort* Bs  = smem + 8192;           // [256][32] (16KB), wave-local rows

    // A: lane stages A row 'lane' into the wave's own copy
    const ushort* Apt = Wt + (size_t)(f0 + lane) * Kpad;
    ushort* AsW = &Asw[lane * 32];
    int arot = (lane >> 2) & 3;
    // B: thread t stages X row (b*256+t); wave w reads rows w*64..w*64+63
    const ushort* Bpt = X + ((size_t)((b << 8) + t)) * Kpad;
    ushort* BsW = &Bs[t * 32];
    int brot = (t >> 2) & 3;

    floatx4 acc[4][4];
    #pragma unroll
    for (int i = 0; i < 4; ++i)
        #pragma unroll
        for (int j = 0; j < 4; ++j) acc[i][j] = (floatx4)0.f;

    const ushort* Ab = &Asw[frow * 32 + rot];
    const ushort* Bb = &Bs[(w * 64 + frow) * 32 + rot];

    int nk1 = Kpad >> 5;
    for (int ks = 0; ks < nk1; ++ks) {
        uint4 pa0 = *(const uint4*)(Apt);
        uint4 pa1 = *(const uint4*)(Apt + 8);
        uint4 pa2 = *(const uint4*)(Apt + 16);
        uint4 pa3 = *(const uint4*)(Apt + 24);
        uint4 pb0 = *(const uint4*)(Bpt);
        uint4 pb1 = *(const uint4*)(Bpt + 8);
        uint4 pb2 = *(const uint4*)(Bpt + 16);
        uint4 pb3 = *(const uint4*)(Bpt + 24);
        Apt += 32; Bpt += 32;
        __builtin_amdgcn_wave_barrier();
        *(uint4*)(AsW + (((0 + arot) & 3) * 8)) = pa0;
        *(uint4*)(AsW + (((1 + arot) & 3) * 8)) = pa1;
        *(uint4*)(AsW + (((2 + arot) & 3) * 8)) = pa2;
        *(uint4*)(AsW + (((3 + arot) & 3) * 8)) = pa3;
        *(uint4*)(BsW + (((0 + brot) & 3) * 8)) = pb0;
        *(uint4*)(BsW + (((1 + brot) & 3) * 8)) = pb1;
        *(uint4*)(BsW + (((2 + brot) & 3) * 8)) = pb2;
        *(uint4*)(BsW + (((3 + brot) & 3) * 8)) = pb3;
        __builtin_amdgcn_wave_barrier();
        short8 af[4], bf[4];
        #pragma unroll
        for (int i = 0; i < 4; ++i) {
            af[i] = u4_frag(*(const uint4*)(Ab + i * 16 * 32));
            bf[i] = u4_frag(*(const uint4*)(Bb + i * 16 * 32));
        }
        #pragma unroll
        for (int i = 0; i < 4; ++i)
            #pragma unroll
            for (int j = 0; j < 4; ++j)
                acc[i][j] = __builtin_amdgcn_mfma_f32_16x16x32_bf16(af[i], bf[j], acc[i][j], 0, 0, 0);
    }

    // issue phase-2 ks=0 S loads NOW: latency hides behind the epilogue barrier
    const ushort* Sp = Sg + (size_t)(w * 64 + frow) * 256 + quad * 8;
    uint4 ps[4];
    #pragma unroll
    for (int i = 0; i < 4; ++i) ps[i] = *(const uint4*)(Sp + i * 4096);

    // epilogue 1 -> Ys (overlays staging; barrier: other waves' staging reads done)
    __syncthreads();
    #pragma unroll
    for (int i = 0; i < 4; ++i)
        #pragma unroll
        for (int r = 0; r < 4; ++r) {
            int f = i * 16 + quad * 4 + r;
            float bv = (f0 + f < Nfeat) ? bias[f0 + f] : 0.f;
            #pragma unroll
            for (int j = 0; j < 4; ++j) {
                // c = w*64 + j*16 + frow ; chunk = c>>5 ; granule gc = (c&31)>>3
                int chunk = 2 * w + (j >> 1);
                int gc = 2 * (j & 1) + (frow >> 3);
                Ys[chunk * YCH + f * 32 + (((gc + quad) & 3) * 8) + (frow & 7)]
                    = f2bf(acc[i][j][r] + bv);
            }
        }
    __syncthreads();

    // ---------------- phase 2 (no barriers, S double-buffered) ----------------
    #pragma unroll
    for (int i = 0; i < 4; ++i)
        #pragma unroll
        for (int j = 0; j < 4; ++j) acc[i][j] = (floatx4)0.f;

    for (int ks = 0; ks < 8; ++ks) {
        uint4 pn[4];
        if (ks < 7) {
            #pragma unroll
            for (int i = 0; i < 4; ++i)
                pn[i] = *(const uint4*)(Sp + i * 4096 + (ks + 1) * 32);
        }
        short8 bf[4];
        #pragma unroll
        for (int j = 0; j < 4; ++j)
            bf[j] = u4_frag(*(const uint4*)(&Ys[ks * YCH + (j * 16 + frow) * 32 + rot]));
        #pragma unroll
        for (int i = 0; i < 4; ++i) {
            short8 af = u4_frag(ps[i]);
            #pragma unroll
            for (int j = 0; j < 4; ++j)
                acc[i][j] = __builtin_amdgcn_mfma_f32_16x16x32_bf16(af, bf[j], acc[i][j], 0, 0, 0);
        }
        #pragma unroll
        for (int i = 0; i < 4; ++i) ps[i] = pn[i];
    }

    // epilogue 2: r = w*64+i*16+quad*4+reg, f = j*16+frow (32B runs)
    #pragma unroll
    for (int i = 0; i < 4; ++i)
        #pragma unroll
        for (int r = 0; r < 4; ++r) {
            int rg = w * 64 + i * 16 + quad * 4 + r;
            ushort* Zr = Z + (size_t)((b << 8) + rg) * FsN + f0;
            #pragma unroll
            for (int j = 0; j < 4; ++j)
                Zr[j * 16 + frow] = f2bf(fmaxf(acc[i][j][r], 0.f));
        }
}

// ---------------- L5 GEMM (N=2): wave/row over padded Mp, bf16 in (stride Kstr), f32 out ----
__global__ __launch_bounds__(256) void gemm_n2_bf16(const ushort* __restrict__ X,
                                                    const float* __restrict__ W,
                                                    const float* __restrict__ bias,
                                                    float* __restrict__ Y,
                                                    int Mp, int K, int Kstr) {
    int wv = (blockIdx.x * blockDim.x + threadIdx.x) >> 6;
    int lane = threadIdx.x & 63;
    if (wv >= Mp) return;
    const uint* Xr = (const uint*)(X + (size_t)wv * Kstr);
    int K2 = K >> 1;
    float a0 = 0.f, a1 = 0.f;
    for (int k2 = lane; k2 < K2; k2 += 64) {
        uint p = Xr[k2];
        float x0 = bf2f((ushort)(p & 0xffffu)), x1 = bf2f((ushort)(p >> 16));
        float4 w = ((const float4*)W)[k2];
        a0 = fmaf(x0, w.x, fmaf(x1, w.z, a0));
        a1 = fmaf(x0, w.y, fmaf(x1, w.w, a1));
    }
    #pragma unroll
    for (int off = 32; off; off >>= 1) {
        a0 += __shfl_down(a0, off);
        a1 += __shfl_down(a1, off);
    }
    if (lane == 0) {
        Y[(size_t)wv * 2]     = a0 + bias[0];
        Y[(size_t)wv * 2 + 1] = a1 + bias[1];
    }
}

// ---------------- final SpMM (F=2) + relu: padded f32 in [b*256+c], compact out ----------------
__global__ __launch_bounds__(256) void spmm_final_k(const float* __restrict__ Y,
                                                    float* __restrict__ Z,
                                                    const int* __restrict__ rowptr,
                                                    const int* __restrict__ cols,
                                                    const float* __restrict__ vals,
                                                    int total) {
    int tt = blockIdx.x * blockDim.x + threadIdx.x;
    if (tt >= total) return;
    int r = tt % NN, b = tt / NN;
    int s = rowptr[r], e = rowptr[r + 1];
    const float* Yb = Y + ((size_t)b << 9);
    float a0 = 0.f, a1 = 0.f;
    for (int i = s; i < e; ++i) {
        float v = vals[i]; int c = cols[i];
        a0 = fmaf(v, Yb[c * 2], a0);
        a1 = fmaf(v, Yb[c * 2 + 1], a1);
    }
    Z[(size_t)tt * 2]     = fmaxf(a0, 0.f);
    Z[(size_t)tt * 2 + 1] = fmaxf(a1, 0.f);
}

extern "C" void kernel_launch(void* const* d_in, const int* in_sizes, int n_in,
                              void* d_out, int out_size, void* d_ws, size_t ws_size,
                              hipStream_t stream) {
    const float* H = (const float*)d_in[0];
    const int*   g_rows[4] = {(const int*)d_in[1], (const int*)d_in[4], (const int*)d_in[7], (const int*)d_in[10]};
    const int*   g_cols[4] = {(const int*)d_in[2], (const int*)d_in[5], (const int*)d_in[8], (const int*)d_in[11]};
    const float* g_vals[4] = {(const float*)d_in[3], (const float*)d_in[6], (const float*)d_in[9], (const float*)d_in[12]};
    const float* W0  = (const float*)d_in[13]; const float* b0  = (const float*)d_in[14];
    const float* W1  = (const float*)d_in[15]; const float* b1  = (const float*)d_in[16];
    const float* W2  = (const float*)d_in[17]; const float* b2  = (const float*)d_in[18];
    const float* Wd0 = (const float*)d_in[19]; const float* bd0 = (const float*)d_in[20];
    const float* Wd1 = (const float*)d_in[21]; const float* bd1 = (const float*)d_in[22];
    const float* Wd2 = (const float*)d_in[23]; const float* bd2 = (const float*)d_in[24];
    float* out = (float*)d_out;

    const int nnz = in_sizes[1];
    const int B   = in_sizes[0] / (NN * 2);   // 256
    const int M   = B * NN;                   // 65280 (compact)
    const int Mp  = B * 256;                  // 65536 (padded)

    // ---- workspace (ushort units) ----
    ushort* bufA = (ushort*)d_ws;                    // N-layout [Mp, <=448]
    ushort* bufB = bufA + (size_t)Mp * 448;          // N-layout [Mp, <=320]
    float*  tmpF = (float*)(bufB + (size_t)Mp * 320);// f32 [Mp, 2]
    ushort* Wt1 = (ushort*)(tmpF + Mp * 2);          // [320,416]
    ushort* Wt2 = Wt1 + 320 * 416;                   // [128,320]
    ushort* Wt3 = Wt2 + 128 * 320;                   // [320,128]
    ushort* Wt4 = Wt3 + 320 * 128;                   // [448,320]
    ushort* Sb  = Wt4 + 448 * 320;                   // 4 x [256,256] bf16
    // contiguous zero region: cnt | fil | rs | Sd
    int*    cnt = (int*)(Sb + 4 * 65536);            // 4*256
    int*    fil = cnt + 4 * 256;                     // 4*256
    float*  rs  = (float*)(fil + 4 * 256);           // 4*256
    float*  Sd  = rs + 4 * 256;                      // 4*65536
    const int ZN = 4 * 256 * 3 + 4 * 65536;          // ints to zero
    int*    rowp = (int*)(Sd + 4 * 65536);           // 4*256
    const int nnzp = (nnz + 63) & ~63;
    int*    ccol = rowp + 4 * 256;
    float*  cval = (float*)(ccol + 4 * nnzp);

    Graphs G;
    for (int i = 0; i < 4; ++i) {
        G.rows[i] = g_rows[i]; G.cols[i] = g_cols[i]; G.vals[i] = g_vals[i];
        G.cnt[i] = cnt + i * 256; G.fill[i] = fil + i * 256; G.rowptr[i] = rowp + i * 256;
        G.csr_col[i] = ccol + i * nnzp; G.csr_val[i] = cval + i * nnzp;
    }

    // setup: 5 launches
    zero_k<<<(ZN + 255) / 256, 256, 0, stream>>>(cnt, ZN);
    edge_k<<<dim3((nnz + 255) / 256, 4), 256, 0, stream>>>(G, Sd, rs, nnz);
    scan_k<<<4, 256, 0, stream>>>(G);
    fill_k<<<dim3((nnz + 255) / 256, 4), 256, 0, stream>>>(G, nnz);
    conv_k<<<(620544 + 255) / 256, 256, 0, stream>>>(Sd, Sb, W1, Wt1, W2, Wt2, Wd0, Wt3, Wd1, Wt4);

    // L0: [2->400] g0, commuted.  H -> tmpF[M,2] -> bufA[Mp,416]
    spmm_f2_f32<<<(M + 255) / 256, 256, 0, stream>>>(H, tmpF, G.rowptr[0], G.csr_col[0], G.csr_val[0], M);
    gemm_k2_relu<<<(Mp * 208 + 255) / 256, 256, 0, stream>>>(tmpF, W0, b0, rs + 0, bufA, Mp, 400, 416);

    // L1: [400->300] g0.  bufA(K416) -> bufB(FsN 320), 5 f-tiles
    fused_layer<<<B * 5, 256, 0, stream>>>(bufA, Wt1, Sb + 0 * 65536, b1, bufB, 416, 300, 320, 5);
    // L2: [300->100] g1.  bufB(K320) -> bufA(FsN 128), 2 f-tiles
    fused_layer<<<B * 2, 256, 0, stream>>>(bufB, Wt2, Sb + 1 * 65536, b2, bufA, 320, 100, 128, 2);
    // L3: [100->300] g3.  bufA(K128) -> bufB(FsN 320), 5 f-tiles
    fused_layer<<<B * 5, 256, 0, stream>>>(bufA, Wt3, Sb + 3 * 65536, bd0, bufB, 128, 300, 320, 5);
    // L4: [300->400] g2.  bufB(K320) -> bufA(FsN 448), 7 f-tiles
    fused_layer<<<B * 7, 256, 0, stream>>>(bufB, Wt4, Sb + 2 * 65536, bd1, bufA, 320, 400, 448, 7);

    // L5: [400->2] g2.  bufA(stride 448, K=400) -> tmpF[Mp,2] -> out[M,2]
    gemm_n2_bf16<<<(Mp * 64 + 255) / 256, 256, 0, stream>>>(bufA, Wd2, bd2, tmpF, Mp, 400, 448);
    spmm_final_k<<<(M + 255) / 256, 256, 0, stream>>>(tmpF, out, G.rowptr[2], G.csr_col[2], G.csr_val[2], M);
}

// Round 14
// 386.225 us; speedup vs baseline: 1.1119x; 1.1119x over previous
//
#include <hip/hip_runtime.h>
#include <hip/hip_bf16.h>

// 6 layers of relu(spmm(graph, x@W+b)), B=256, NN=255 nodes.
// R13 = R11 (417us anchor) + software-pipelined phase-1 staging:
// global loads for chunk ks+1 are issued AFTER barrier 2 (in flight across
// the MFMA section), instead of immediately before barrier 1 where the
// barrier's implicit s_waitcnt vmcnt(0) serialized the full load latency
// every k-step. Everything else identical to R11.

#define NN 255
#define YCH 2048           // ushorts per Y k-chunk: 64 rows * 32

typedef __attribute__((ext_vector_type(8))) short short8;
typedef __attribute__((ext_vector_type(4))) float floatx4;

__device__ __forceinline__ float bf2f(ushort u) {
    union { uint u; float f; } c; c.u = ((uint)u) << 16; return c.f;
}
__device__ __forceinline__ ushort f2bf(float f) {
    union { float f; uint u; } c; c.f = f;
    uint u = c.u + 0x7fff + ((c.u >> 16) & 1);
    return (ushort)(u >> 16);
}
__device__ __forceinline__ short8 u4_frag(uint4 v) {
    union { uint4 u; short8 s; } c; c.u = v; return c.s;
}

// ---------------- graph preprocessing ----------------
struct Graphs {
    const int*   rows[4];
    const int*   cols[4];
    const float* vals[4];
    int*   cnt[4];
    int*   fill[4];
    int*   rowptr[4];
    int*   csr_col[4];
    float* csr_val[4];
};

__global__ void zero_k(int* p, int n) {
    int i = blockIdx.x * blockDim.x + threadIdx.x;
    if (i < n) p[i] = 0;
}

// per-edge: histogram count + dense-S scatter + rowsum, all atomics
__global__ void edge_k(Graphs g, float* Sd, float* rs, int nnz) {
    int gi = blockIdx.y;
    int e = blockIdx.x * blockDim.x + threadIdx.x;
    if (e < nnz) {
        int r = g.rows[gi][e], c = g.cols[gi][e];
        float v = g.vals[gi][e];
        atomicAdd(&g.cnt[gi][r], 1);
        atomicAdd(&Sd[gi * 65536 + r * 256 + c], v);
        atomicAdd(&rs[gi * 256 + r], v);
    }
}

// parallel exclusive scan over 255 counts -> rowptr[256] (per graph)
__global__ void scan_k(Graphs g) {
    __shared__ int buf[256];
    int gi = blockIdx.x, t = threadIdx.x;
    int v = (t < NN) ? g.cnt[gi][t] : 0;
    buf[t] = v;
    __syncthreads();
    #pragma unroll
    for (int off = 1; off < 256; off <<= 1) {
        int x = (t >= off) ? buf[t - off] : 0;
        __syncthreads();
        buf[t] += x;
        __syncthreads();
    }
    g.rowptr[gi][t] = buf[t] - v;   // exclusive; t=255 gives total (v=0)
}

__global__ void fill_k(Graphs g, int nnz) {
    int gi = blockIdx.y;
    int e = blockIdx.x * blockDim.x + threadIdx.x;
    if (e < nnz) {
        int r = g.rows[gi][e];
        int p = g.rowptr[gi][r] + atomicAdd(&g.fill[gi][r], 1);
        g.csr_col[gi][p] = g.cols[gi][e];
        g.csr_val[gi][p] = g.vals[gi][e];
    }
}

// merged converts: Sd->Sb (bf16) then 4 weight transposes (ladder on idx)
__device__ __forceinline__ void wpiece(const float* __restrict__ W, ushort* __restrict__ Wt,
                                       int K, int N, int Kpad, int idx) {
    int n = idx / Kpad, k = idx - n * Kpad;
    float v = (n < N && k < K) ? W[(size_t)k * N + n] : 0.f;
    Wt[idx] = f2bf(v);
}

__global__ void conv_k(const float* __restrict__ Sd, ushort* __restrict__ Sb,
                       const float* __restrict__ W1, ushort* __restrict__ Wt1,
                       const float* __restrict__ W2, ushort* __restrict__ Wt2,
                       const float* __restrict__ W3, ushort* __restrict__ Wt3,
                       const float* __restrict__ W4, ushort* __restrict__ Wt4) {
    int idx = blockIdx.x * blockDim.x + threadIdx.x;
    if (idx < 262144) { Sb[idx] = f2bf(Sd[idx]); return; }
    idx -= 262144;
    if (idx < 133120) { wpiece(W1, Wt1, 400, 300, 416, idx); return; }
    idx -= 133120;
    if (idx < 40960)  { wpiece(W2, Wt2, 300, 100, 320, idx); return; }
    idx -= 40960;
    if (idx < 40960)  { wpiece(W3, Wt3, 100, 300, 128, idx); return; }
    idx -= 40960;
    if (idx < 143360) { wpiece(W4, Wt4, 300, 400, 320, idx); }
}

// ---------------- L0 spmm: F=2, f32 in (H, compact), f32 out ----------------
__global__ __launch_bounds__(256) void spmm_f2_f32(const float* __restrict__ H,
                                                   float* __restrict__ T,
                                                   const int* __restrict__ rowptr,
                                                   const int* __restrict__ cols,
                                                   const float* __restrict__ vals,
                                                   int total) {
    int tt = blockIdx.x * blockDim.x + threadIdx.x;
    if (tt >= total) return;
    int r = tt % NN, b = tt / NN;
    int s = rowptr[r], e = rowptr[r + 1];
    const float* Hb = H + (size_t)b * NN * 2;
    float a0 = 0.f, a1 = 0.f;
    for (int i = s; i < e; ++i) {
        float v = vals[i]; int c = cols[i];
        a0 = fmaf(v, Hb[c * 2], a0);
        a1 = fmaf(v, Hb[c * 2 + 1], a1);
    }
    T[(size_t)tt * 2] = a0;
    T[(size_t)tt * 2 + 1] = a1;
}

// -------- L0 GEMM (K=2): relu(acc + rs[node]*b[n]) -> N-layout [b*256+node][416] --------
__global__ __launch_bounds__(256) void gemm_k2_relu(const float* __restrict__ T,
                                                    const float* __restrict__ W,
                                                    const float* __restrict__ bias,
                                                    const float* __restrict__ rs,
                                                    ushort* __restrict__ Y,
                                                    int Mp, int N, int Ns) {
    int half = Ns >> 1;    // 208
    int idx = blockIdx.x * blockDim.x + threadIdx.x;
    if (idx >= Mp * half) return;
    int m = idx / half, n2 = (idx - m * half) * 2;
    int node = m & 255, b = m >> 8;
    uint o = 0;
    if (n2 < N && node < NN) {
        int mc = b * NN + node;
        float x0 = T[mc * 2], x1 = T[mc * 2 + 1];
        float rsm = rs[node];
        float y0 = fmaf(x0, W[n2],     fmaf(x1, W[N + n2],     rsm * bias[n2]));
        float y1 = fmaf(x0, W[n2 + 1], fmaf(x1, W[N + n2 + 1], rsm * bias[n2 + 1]));
        o = (uint)f2bf(fmaxf(y0, 0.f)) | ((uint)f2bf(fmaxf(y1, 0.f)) << 16);
    }
    ((uint*)Y)[idx] = o;
}

// =======================================================================
// Fused layer: block = (batch b, 64-feature tile ft).
//   phase 1: Y[64f,256c] = Wt_tile @ X_b^T + bias  (A+B staged in LDS,
//            2 barriers/k-step, staging loads software-pipelined 1 step ahead)
//   phase 2: Z[256r,64f] = relu(S @ Y)             (S from L2 double-buffered, Y from LDS)
// LDS layout (rotation): row stride 32 ushorts (64B); 16B granule g of row r
// lives at position (g + (r>>2))&3. All frag ops are aligned b128.
// =======================================================================
__global__ __launch_bounds__(256, 3) void fused_layer(const ushort* __restrict__ X,
                                                      const ushort* __restrict__ Wt,
                                                      const ushort* __restrict__ Sg,
                                                      const float* __restrict__ bias,
                                                      ushort* __restrict__ Z,
                                                      int Kpad, int Nfeat, int FsN,
                                                      int nft) {
    __shared__ ushort smem[8 * YCH];     // 32768 B total -> 5 blocks/CU
    ushort* As = smem;                   // [64][32]  phase-1 A staging
    ushort* Bs = smem + 64 * 32;         // [256][32] phase-1 B staging
    ushort* Ys = smem;                   // overlay: 8 chunks of [64][32]

    int li = blockIdx.x;
    int x = li & 7, rr = li >> 3;
    int ft = rr % nft, b = (rr / nft) * 8 + x;
    int f0 = ft * 64;

    int t = threadIdx.x;
    int w = t >> 6, lane = t & 63;
    int frow = lane & 15, quad = lane >> 4;
    int rot = ((quad + (frow >> 2)) & 3) * 8;   // frag-read granule offset (ushorts)

    // ---------------- phase 1 ----------------
    const ushort* Xb = X + (((size_t)b) << 8) * Kpad;
    const ushort* Apt = Wt + (size_t)(f0 + (t >> 2)) * Kpad + ((t & 3) * 8);
    const ushort* Bpt = Xb + (size_t)t * Kpad;
    // staging write targets (rotated)
    ushort* AsW = &As[(t >> 2) * 32 + (((t & 3) + ((t >> 4) & 3)) & 3) * 8];
    ushort* BsW = &Bs[t * 32];
    int brot = (t >> 2) & 3;                    // B row rotation for this thread

    floatx4 acc[4][4];
    #pragma unroll
    for (int i = 0; i < 4; ++i)
        #pragma unroll
        for (int j = 0; j < 4; ++j) acc[i][j] = (floatx4)0.f;

    const ushort* Ab = &As[frow * 32 + rot];
    const ushort* Bb = &Bs[(w * 64 + frow) * 32 + rot];

    int nk1 = Kpad >> 5;
    // prologue: prefetch chunk 0
    uint4 pa  = *(const uint4*)(Apt);
    uint4 pb0 = *(const uint4*)(Bpt);
    uint4 pb1 = *(const uint4*)(Bpt + 8);
    uint4 pb2 = *(const uint4*)(Bpt + 16);
    uint4 pb3 = *(const uint4*)(Bpt + 24);
    Apt += 32; Bpt += 32;

    for (int ks = 0; ks < nk1; ++ks) {
        __syncthreads();                 // prev iter's frag reads done
        *(uint4*)AsW = pa;
        *(uint4*)(BsW + (((0 + brot) & 3) * 8)) = pb0;
        *(uint4*)(BsW + (((1 + brot) & 3) * 8)) = pb1;
        *(uint4*)(BsW + (((2 + brot) & 3) * 8)) = pb2;
        *(uint4*)(BsW + (((3 + brot) & 3) * 8)) = pb3;
        __syncthreads();
        if (ks + 1 < nk1) {              // prefetch chunk ks+1: in flight across MFMAs
            pa  = *(const uint4*)(Apt);
            pb0 = *(const uint4*)(Bpt);
            pb1 = *(const uint4*)(Bpt + 8);
            pb2 = *(const uint4*)(Bpt + 16);
            pb3 = *(const uint4*)(Bpt + 24);
            Apt += 32; Bpt += 32;
        }
        short8 af[4], bf[4];
        #pragma unroll
        for (int i = 0; i < 4; ++i) {
            af[i] = u4_frag(*(const uint4*)(Ab + i * 16 * 32));
            bf[i] = u4_frag(*(const uint4*)(Bb + i * 16 * 32));
        }
        #pragma unroll
        for (int i = 0; i < 4; ++i)
            #pragma unroll
            for (int j = 0; j < 4; ++j)
                acc[i][j] = __builtin_amdgcn_mfma_f32_16x16x32_bf16(af[i], bf[j], acc[i][j], 0, 0, 0);
    }

    // issue phase-2 ks=0 S loads NOW: latency hides behind the epilogue barrier
    const ushort* Sp = Sg + (size_t)(w * 64 + frow) * 256 + quad * 8;
    uint4 ps[4];
    #pragma unroll
    for (int i = 0; i < 4; ++i) ps[i] = *(const uint4*)(Sp + i * 4096);

    // epilogue 1 -> Ys (overlays staging; barrier ensures frag reads done)
    __syncthreads();
    #pragma unroll
    for (int i = 0; i < 4; ++i)
        #pragma unroll
        for (int r = 0; r < 4; ++r) {
            int f = i * 16 + quad * 4 + r;
            float bv = (f0 + f < Nfeat) ? bias[f0 + f] : 0.f;
            #pragma unroll
            for (int j = 0; j < 4; ++j) {
                // c = w*64 + j*16 + frow ; chunk = c>>5 ; granule gc = (c&31)>>3
                int chunk = 2 * w + (j >> 1);
                int gc = 2 * (j & 1) + (frow >> 3);
                Ys[chunk * YCH + f * 32 + (((gc + quad) & 3) * 8) + (frow & 7)]
                    = f2bf(acc[i][j][r] + bv);
            }
        }
    __syncthreads();

    // ---------------- phase 2 (no barriers, S double-buffered) ----------------
    #pragma unroll
    for (int i = 0; i < 4; ++i)
        #pragma unroll
        for (int j = 0; j < 4; ++j) acc[i][j] = (floatx4)0.f;

    for (int ks = 0; ks < 8; ++ks) {
        uint4 pn[4];
        if (ks < 7) {
            #pragma unroll
            for (int i = 0; i < 4; ++i)
                pn[i] = *(const uint4*)(Sp + i * 4096 + (ks + 1) * 32);
        }
        short8 bf[4];
        #pragma unroll
        for (int j = 0; j < 4; ++j)
            bf[j] = u4_frag(*(const uint4*)(&Ys[ks * YCH + (j * 16 + frow) * 32 + rot]));
        #pragma unroll
        for (int i = 0; i < 4; ++i) {
            short8 af = u4_frag(ps[i]);
            #pragma unroll
            for (int j = 0; j < 4; ++j)
                acc[i][j] = __builtin_amdgcn_mfma_f32_16x16x32_bf16(af, bf[j], acc[i][j], 0, 0, 0);
        }
        #pragma unroll
        for (int i = 0; i < 4; ++i) ps[i] = pn[i];
    }

    // epilogue 2: r = w*64+i*16+quad*4+reg, f = j*16+frow (32B runs)
    #pragma unroll
    for (int i = 0; i < 4; ++i)
        #pragma unroll
        for (int r = 0; r < 4; ++r) {
            int rg = w * 64 + i * 16 + quad * 4 + r;
            ushort* Zr = Z + (size_t)((b << 8) + rg) * FsN + f0;
            #pragma unroll
            for (int j = 0; j < 4; ++j)
                Zr[j * 16 + frow] = f2bf(fmaxf(acc[i][j][r], 0.f));
        }
}

// ---------------- L5 GEMM (N=2): wave/row over padded Mp, bf16 in (stride Kstr), f32 out ----
__global__ __launch_bounds__(256) void gemm_n2_bf16(const ushort* __restrict__ X,
                                                    const float* __restrict__ W,
                                                    const float* __restrict__ bias,
                                                    float* __restrict__ Y,
                                                    int Mp, int K, int Kstr) {
    int wv = (blockIdx.x * blockDim.x + threadIdx.x) >> 6;
    int lane = threadIdx.x & 63;
    if (wv >= Mp) return;
    const uint* Xr = (const uint*)(X + (size_t)wv * Kstr);
    int K2 = K >> 1;
    float a0 = 0.f, a1 = 0.f;
    for (int k2 = lane; k2 < K2; k2 += 64) {
        uint p = Xr[k2];
        float x0 = bf2f((ushort)(p & 0xffffu)), x1 = bf2f((ushort)(p >> 16));
        float4 w = ((const float4*)W)[k2];
        a0 = fmaf(x0, w.x, fmaf(x1, w.z, a0));
        a1 = fmaf(x0, w.y, fmaf(x1, w.w, a1));
    }
    #pragma unroll
    for (int off = 32; off; off >>= 1) {
        a0 += __shfl_down(a0, off);
        a1 += __shfl_down(a1, off);
    }
    if (lane == 0) {
        Y[(size_t)wv * 2]     = a0 + bias[0];
        Y[(size_t)wv * 2 + 1] = a1 + bias[1];
    }
}

// ---------------- final SpMM (F=2) + relu: padded f32 in [b*256+c], compact out ----------------
__global__ __launch_bounds__(256) void spmm_final_k(const float* __restrict__ Y,
                                                    float* __restrict__ Z,
                                                    const int* __restrict__ rowptr,
                                                    const int* __restrict__ cols,
                                                    const float* __restrict__ vals,
                                                    int total) {
    int tt = blockIdx.x * blockDim.x + threadIdx.x;
    if (tt >= total) return;
    int r = tt % NN, b = tt / NN;
    int s = rowptr[r], e = rowptr[r + 1];
    const float* Yb = Y + ((size_t)b << 9);
    float a0 = 0.f, a1 = 0.f;
    for (int i = s; i < e; ++i) {
        float v = vals[i]; int c = cols[i];
        a0 = fmaf(v, Yb[c * 2], a0);
        a1 = fmaf(v, Yb[c * 2 + 1], a1);
    }
    Z[(size_t)tt * 2]     = fmaxf(a0, 0.f);
    Z[(size_t)tt * 2 + 1] = fmaxf(a1, 0.f);
}

extern "C" void kernel_launch(void* const* d_in, const int* in_sizes, int n_in,
                              void* d_out, int out_size, void* d_ws, size_t ws_size,
                              hipStream_t stream) {
    const float* H = (const float*)d_in[0];
    const int*   g_rows[4] = {(const int*)d_in[1], (const int*)d_in[4], (const int*)d_in[7], (const int*)d_in[10]};
    const int*   g_cols[4] = {(const int*)d_in[2], (const int*)d_in[5], (const int*)d_in[8], (const int*)d_in[11]};
    const float* g_vals[4] = {(const float*)d_in[3], (const float*)d_in[6], (const float*)d_in[9], (const float*)d_in[12]};
    const float* W0  = (const float*)d_in[13]; const float* b0  = (const float*)d_in[14];
    const float* W1  = (const float*)d_in[15]; const float* b1  = (const float*)d_in[16];
    const float* W2  = (const float*)d_in[17]; const float* b2  = (const float*)d_in[18];
    const float* Wd0 = (const float*)d_in[19]; const float* bd0 = (const float*)d_in[20];
    const float* Wd1 = (const float*)d_in[21]; const float* bd1 = (const float*)d_in[22];
    const float* Wd2 = (const float*)d_in[23]; const float* bd2 = (const float*)d_in[24];
    float* out = (float*)d_out;

    const int nnz = in_sizes[1];
    const int B   = in_sizes[0] / (NN * 2);   // 256
    const int M   = B * NN;                   // 65280 (compact)
    const int Mp  = B * 256;                  // 65536 (padded)

    // ---- workspace (ushort units) ----
    ushort* bufA = (ushort*)d_ws;                    // N-layout [Mp, <=448]
    ushort* bufB = bufA + (size_t)Mp * 448;          // N-layout [Mp, <=320]
    float*  tmpF = (float*)(bufB + (size_t)Mp * 320);// f32 [Mp, 2]
    ushort* Wt1 = (ushort*)(tmpF + Mp * 2);          // [320,416]
    ushort* Wt2 = Wt1 + 320 * 416;                   // [128,320]
    ushort* Wt3 = Wt2 + 128 * 320;                   // [320,128]
    ushort* Wt4 = Wt3 + 320 * 128;                   // [448,320]
    ushort* Sb  = Wt4 + 448 * 320;                   // 4 x [256,256] bf16
    // contiguous zero region: cnt | fil | rs | Sd
    int*    cnt = (int*)(Sb + 4 * 65536);            // 4*256
    int*    fil = cnt + 4 * 256;                     // 4*256
    float*  rs  = (float*)(fil + 4 * 256);           // 4*256
    float*  Sd  = rs + 4 * 256;                      // 4*65536
    const int ZN = 4 * 256 * 3 + 4 * 65536;          // ints to zero
    int*    rowp = (int*)(Sd + 4 * 65536);           // 4*256
    const int nnzp = (nnz + 63) & ~63;
    int*    ccol = rowp + 4 * 256;
    float*  cval = (float*)(ccol + 4 * nnzp);

    Graphs G;
    for (int i = 0; i < 4; ++i) {
        G.rows[i] = g_rows[i]; G.cols[i] = g_cols[i]; G.vals[i] = g_vals[i];
        G.cnt[i] = cnt + i * 256; G.fill[i] = fil + i * 256; G.rowptr[i] = rowp + i * 256;
        G.csr_col[i] = ccol + i * nnzp; G.csr_val[i] = cval + i * nnzp;
    }

    // setup: 5 launches
    zero_k<<<(ZN + 255) / 256, 256, 0, stream>>>(cnt, ZN);
    edge_k<<<dim3((nnz + 255) / 256, 4), 256, 0, stream>>>(G, Sd, rs, nnz);
    scan_k<<<4, 256, 0, stream>>>(G);
    fill_k<<<dim3((nnz + 255) / 256, 4), 256, 0, stream>>>(G, nnz);
    conv_k<<<(620544 + 255) / 256, 256, 0, stream>>>(Sd, Sb, W1, Wt1, W2, Wt2, Wd0, Wt3, Wd1, Wt4);

    // L0: [2->400] g0, commuted.  H -> tmpF[M,2] -> bufA[Mp,416]
    spmm_f2_f32<<<(M + 255) / 256, 256, 0, stream>>>(H, tmpF, G.rowptr[0], G.csr_col[0], G.csr_val[0], M);
    gemm_k2_relu<<<(Mp * 208 + 255) / 256, 256, 0, stream>>>(tmpF, W0, b0, rs + 0, bufA, Mp, 400, 416);

    // L1: [400->300] g0.  bufA(K416) -> bufB(FsN 320), 5 f-tiles
    fused_layer<<<B * 5, 256, 0, stream>>>(bufA, Wt1, Sb + 0 * 65536, b1, bufB, 416, 300, 320, 5);
    // L2: [300->100] g1.  bufB(K320) -> bufA(FsN 128), 2 f-tiles
    fused_layer<<<B * 2, 256, 0, stream>>>(bufB, Wt2, Sb + 1 * 65536, b2, bufA, 320, 100, 128, 2);
    // L3: [100->300] g3.  bufA(K128) -> bufB(FsN 320), 5 f-tiles
    fused_layer<<<B * 5, 256, 0, stream>>>(bufA, Wt3, Sb + 3 * 65536, bd0, bufB, 128, 300, 320, 5);
    // L4: [300->400] g2.  bufB(K320) -> bufA(FsN 448), 7 f-tiles
    fused_layer<<<B * 7, 256, 0, stream>>>(bufB, Wt4, Sb + 2 * 65536, bd1, bufA, 320, 400, 448, 7);

    // L5: [400->2] g2.  bufA(stride 448, K=400) -> tmpF[Mp,2] -> out[M,2]
    gemm_n2_bf16<<<(Mp * 64 + 255) / 256, 256, 0, stream>>>(bufA, Wd2, bd2, tmpF, Mp, 400, 448);
    spmm_final_k<<<(M + 255) / 256, 256, 0, stream>>>(tmpF, out, G.rowptr[2], G.csr_col[2], G.csr_val[2], M);
}

// Round 15
// 381.535 us; speedup vs baseline: 1.1255x; 1.0123x over previous
//
#include <hip/hip_runtime.h>
#include <hip/hip_bf16.h>

// 6 layers of relu(spmm(graph, x@W+b)), B=256, NN=255 nodes.
// R14 = R13 (386us anchor: software-pipelined fused dense+spmm layers) +
// non-fused tail shrink:
//   - CSR deleted (scan_k/fill_k gone); L0/L5 spmm specials use dense f32 Sd
//     (row/col 255 zero by construction).
//   - L0 = spmm_f2 + gemm_k2_relu merged into one block-per-batch kernel
//     (2KB intermediate in LDS; phase C re-linearized for coalesced writes).
//   - L5 = gemm_n2 + spmm_final merged likewise.
//   - 13 -> 9 launches. fused_layer untouched from R13.

#define NN 255
#define YCH 2048           // ushorts per Y k-chunk: 64 rows * 32

typedef __attribute__((ext_vector_type(8))) short short8;
typedef __attribute__((ext_vector_type(4))) float floatx4;

__device__ __forceinline__ float bf2f(ushort u) {
    union { uint u; float f; } c; c.u = ((uint)u) << 16; return c.f;
}
__device__ __forceinline__ ushort f2bf(float f) {
    union { float f; uint u; } c; c.f = f;
    uint u = c.u + 0x7fff + ((c.u >> 16) & 1);
    return (ushort)(u >> 16);
}
__device__ __forceinline__ short8 u4_frag(uint4 v) {
    union { uint4 u; short8 s; } c; c.u = v; return c.s;
}

// ---------------- graph preprocessing ----------------
__global__ void zero_k(int* p, int n) {
    int i = blockIdx.x * blockDim.x + threadIdx.x;
    if (i < n) p[i] = 0;
}

// per-edge: dense-S scatter + rowsum (f32 atomics)
__global__ void edge_k(const int* __restrict__ r0, const int* __restrict__ c0, const float* __restrict__ v0,
                       const int* __restrict__ r1, const int* __restrict__ c1, const float* __restrict__ v1,
                       const int* __restrict__ r2, const int* __restrict__ c2, const float* __restrict__ v2,
                       const int* __restrict__ r3, const int* __restrict__ c3, const float* __restrict__ v3,
                       float* Sd, float* rs, int nnz) {
    int gi = blockIdx.y;
    int e = blockIdx.x * blockDim.x + threadIdx.x;
    if (e >= nnz) return;
    const int* rr = gi == 0 ? r0 : gi == 1 ? r1 : gi == 2 ? r2 : r3;
    const int* cc = gi == 0 ? c0 : gi == 1 ? c1 : gi == 2 ? c2 : c3;
    const float* vv = gi == 0 ? v0 : gi == 1 ? v1 : gi == 2 ? v2 : v3;
    int r = rr[e], c = cc[e];
    float v = vv[e];
    atomicAdd(&Sd[gi * 65536 + r * 256 + c], v);
    atomicAdd(&rs[gi * 256 + r], v);
}

// merged converts: Sd->Sb (bf16) then 4 weight transposes (ladder on idx)
__device__ __forceinline__ void wpiece(const float* __restrict__ W, ushort* __restrict__ Wt,
                                       int K, int N, int Kpad, int idx) {
    int n = idx / Kpad, k = idx - n * Kpad;
    float v = (n < N && k < K) ? W[(size_t)k * N + n] : 0.f;
    Wt[idx] = f2bf(v);
}

__global__ void conv_k(const float* __restrict__ Sd, ushort* __restrict__ Sb,
                       const float* __restrict__ W1, ushort* __restrict__ Wt1,
                       const float* __restrict__ W2, ushort* __restrict__ Wt2,
                       const float* __restrict__ W3, ushort* __restrict__ Wt3,
                       const float* __restrict__ W4, ushort* __restrict__ Wt4) {
    int idx = blockIdx.x * blockDim.x + threadIdx.x;
    if (idx < 262144) { Sb[idx] = f2bf(Sd[idx]); return; }
    idx -= 262144;
    if (idx < 133120) { wpiece(W1, Wt1, 400, 300, 416, idx); return; }
    idx -= 133120;
    if (idx < 40960)  { wpiece(W2, Wt2, 300, 100, 320, idx); return; }
    idx -= 40960;
    if (idx < 40960)  { wpiece(W3, Wt3, 100, 300, 128, idx); return; }
    idx -= 40960;
    if (idx < 143360) { wpiece(W4, Wt4, 300, 400, 320, idx); }
}

// ---------------- L0 fused: spmm(F=2, dense Sd, f32) -> gemm K=2 + relu ----------------
// block = batch b. Out: N-layout bf16 [b*256+node][416], only cols 0..399 written
// (k-pad cols killed downstream by Wt zero-pad).
__global__ __launch_bounds__(256) void l0_fused(const float* __restrict__ H,
                                                const float* __restrict__ Sd0,
                                                const float* __restrict__ W0,
                                                const float* __restrict__ b0,
                                                const float* __restrict__ rs0,
                                                ushort* __restrict__ Y) {
    __shared__ float hsh[512];      // H_b [256][2], slot 255 = 0
    __shared__ float ssh[512];      // spmm result [256][2]
    int b = blockIdx.x, t = threadIdx.x;
    if (t < NN) {
        hsh[t * 2]     = H[((size_t)b * NN + t) * 2];
        hsh[t * 2 + 1] = H[((size_t)b * NN + t) * 2 + 1];
    } else {
        hsh[t * 2] = 0.f; hsh[t * 2 + 1] = 0.f;
    }
    __syncthreads();
    // dense spmm row t (Sd row 255 is zero; col 255 maps to zeroed LDS slot)
    const float4* Sr = (const float4*)(Sd0 + (size_t)t * 256);
    float s0 = 0.f, s1 = 0.f;
    #pragma unroll 8
    for (int c4 = 0; c4 < 64; ++c4) {
        float4 v = Sr[c4];
        const float2* hp = (const float2*)&hsh[c4 * 8];
        float2 h0 = hp[0], h1 = hp[1], h2 = hp[2], h3 = hp[3];
        s0 = fmaf(v.x, h0.x, s0); s1 = fmaf(v.x, h0.y, s1);
        s0 = fmaf(v.y, h1.x, s0); s1 = fmaf(v.y, h1.y, s1);
        s0 = fmaf(v.z, h2.x, s0); s1 = fmaf(v.z, h2.y, s1);
        s0 = fmaf(v.w, h3.x, s0); s1 = fmaf(v.w, h3.y, s1);
    }
    ssh[t * 2] = s0; ssh[t * 2 + 1] = s1;
    __syncthreads();
    // gemm K=2 with commuted bias rs[node]*b0[n] + relu; linearized for coalescing
    uint* out = (uint*)(Y + (((size_t)b) << 8) * 416);
    for (int i = 0; i < 200; ++i) {
        int idx = i * 256 + t;                 // 256*200 = 51200 live uints
        int m = idx / 200, n2 = idx - m * 200;
        int n = n2 * 2;
        float x0 = ssh[m * 2], x1 = ssh[m * 2 + 1];
        float rsm = rs0[m];
        float y0 = fmaf(x0, W0[n],     fmaf(x1, W0[400 + n],     rsm * b0[n]));
        float y1 = fmaf(x0, W0[n + 1], fmaf(x1, W0[400 + n + 1], rsm * b0[n + 1]));
        out[(size_t)m * 208 + n2] =
            (uint)f2bf(fmaxf(y0, 0.f)) | ((uint)f2bf(fmaxf(y1, 0.f)) << 16);
    }
}

// =======================================================================
// Fused layer (R13, unchanged): block = (batch b, 64-feature tile ft).
//   phase 1: Y[64f,256c] = Wt_tile @ X_b^T + bias  (A+B staged in LDS,
//            2 barriers/k-step, staging loads software-pipelined 1 step ahead)
//   phase 2: Z[256r,64f] = relu(S @ Y)             (S from L2 double-buffered, Y from LDS)
// LDS layout (rotation): row stride 32 ushorts (64B); 16B granule g of row r
// lives at position (g + (r>>2))&3. All frag ops are aligned b128.
// =======================================================================
__global__ __launch_bounds__(256, 3) void fused_layer(const ushort* __restrict__ X,
                                                      const ushort* __restrict__ Wt,
                                                      const ushort* __restrict__ Sg,
                                                      const float* __restrict__ bias,
                                                      ushort* __restrict__ Z,
                                                      int Kpad, int Nfeat, int FsN,
                                                      int nft) {
    __shared__ ushort smem[8 * YCH];     // 32768 B total -> 5 blocks/CU
    ushort* As = smem;                   // [64][32]  phase-1 A staging
    ushort* Bs = smem + 64 * 32;         // [256][32] phase-1 B staging
    ushort* Ys = smem;                   // overlay: 8 chunks of [64][32]

    int li = blockIdx.x;
    int x = li & 7, rr = li >> 3;
    int ft = rr % nft, b = (rr / nft) * 8 + x;
    int f0 = ft * 64;

    int t = threadIdx.x;
    int w = t >> 6, lane = t & 63;
    int frow = lane & 15, quad = lane >> 4;
    int rot = ((quad + (frow >> 2)) & 3) * 8;   // frag-read granule offset (ushorts)

    // ---------------- phase 1 ----------------
    const ushort* Xb = X + (((size_t)b) << 8) * Kpad;
    const ushort* Apt = Wt + (size_t)(f0 + (t >> 2)) * Kpad + ((t & 3) * 8);
    const ushort* Bpt = Xb + (size_t)t * Kpad;
    ushort* AsW = &As[(t >> 2) * 32 + (((t & 3) + ((t >> 4) & 3)) & 3) * 8];
    ushort* BsW = &Bs[t * 32];
    int brot = (t >> 2) & 3;

    floatx4 acc[4][4];
    #pragma unroll
    for (int i = 0; i < 4; ++i)
        #pragma unroll
        for (int j = 0; j < 4; ++j) acc[i][j] = (floatx4)0.f;

    const ushort* Ab = &As[frow * 32 + rot];
    const ushort* Bb = &Bs[(w * 64 + frow) * 32 + rot];

    int nk1 = Kpad >> 5;
    uint4 pa  = *(const uint4*)(Apt);
    uint4 pb0 = *(const uint4*)(Bpt);
    uint4 pb1 = *(const uint4*)(Bpt + 8);
    uint4 pb2 = *(const uint4*)(Bpt + 16);
    uint4 pb3 = *(const uint4*)(Bpt + 24);
    Apt += 32; Bpt += 32;

    for (int ks = 0; ks < nk1; ++ks) {
        __syncthreads();                 // prev iter's frag reads done
        *(uint4*)AsW = pa;
        *(uint4*)(BsW + (((0 + brot) & 3) * 8)) = pb0;
        *(uint4*)(BsW + (((1 + brot) & 3) * 8)) = pb1;
        *(uint4*)(BsW + (((2 + brot) & 3) * 8)) = pb2;
        *(uint4*)(BsW + (((3 + brot) & 3) * 8)) = pb3;
        __syncthreads();
        if (ks + 1 < nk1) {              // prefetch chunk ks+1: in flight across MFMAs
            pa  = *(const uint4*)(Apt);
            pb0 = *(const uint4*)(Bpt);
            pb1 = *(const uint4*)(Bpt + 8);
            pb2 = *(const uint4*)(Bpt + 16);
            pb3 = *(const uint4*)(Bpt + 24);
            Apt += 32; Bpt += 32;
        }
        short8 af[4], bf[4];
        #pragma unroll
        for (int i = 0; i < 4; ++i) {
            af[i] = u4_frag(*(const uint4*)(Ab + i * 16 * 32));
            bf[i] = u4_frag(*(const uint4*)(Bb + i * 16 * 32));
        }
        #pragma unroll
        for (int i = 0; i < 4; ++i)
            #pragma unroll
            for (int j = 0; j < 4; ++j)
                acc[i][j] = __builtin_amdgcn_mfma_f32_16x16x32_bf16(af[i], bf[j], acc[i][j], 0, 0, 0);
    }

    // issue phase-2 ks=0 S loads NOW: latency hides behind the epilogue barrier
    const ushort* Sp = Sg + (size_t)(w * 64 + frow) * 256 + quad * 8;
    uint4 ps[4];
    #pragma unroll
    for (int i = 0; i < 4; ++i) ps[i] = *(const uint4*)(Sp + i * 4096);

    // epilogue 1 -> Ys (overlays staging; barrier ensures frag reads done)
    __syncthreads();
    #pragma unroll
    for (int i = 0; i < 4; ++i)
        #pragma unroll
        for (int r = 0; r < 4; ++r) {
            int f = i * 16 + quad * 4 + r;
            float bv = (f0 + f < Nfeat) ? bias[f0 + f] : 0.f;
            #pragma unroll
            for (int j = 0; j < 4; ++j) {
                int chunk = 2 * w + (j >> 1);
                int gc = 2 * (j & 1) + (frow >> 3);
                Ys[chunk * YCH + f * 32 + (((gc + quad) & 3) * 8) + (frow & 7)]
                    = f2bf(acc[i][j][r] + bv);
            }
        }
    __syncthreads();

    // ---------------- phase 2 (no barriers, S double-buffered) ----------------
    #pragma unroll
    for (int i = 0; i < 4; ++i)
        #pragma unroll
        for (int j = 0; j < 4; ++j) acc[i][j] = (floatx4)0.f;

    for (int ks = 0; ks < 8; ++ks) {
        uint4 pn[4];
        if (ks < 7) {
            #pragma unroll
            for (int i = 0; i < 4; ++i)
                pn[i] = *(const uint4*)(Sp + i * 4096 + (ks + 1) * 32);
        }
        short8 bf[4];
        #pragma unroll
        for (int j = 0; j < 4; ++j)
            bf[j] = u4_frag(*(const uint4*)(&Ys[ks * YCH + (j * 16 + frow) * 32 + rot]));
        #pragma unroll
        for (int i = 0; i < 4; ++i) {
            short8 af = u4_frag(ps[i]);
            #pragma unroll
            for (int j = 0; j < 4; ++j)
                acc[i][j] = __builtin_amdgcn_mfma_f32_16x16x32_bf16(af, bf[j], acc[i][j], 0, 0, 0);
        }
        #pragma unroll
        for (int i = 0; i < 4; ++i) ps[i] = pn[i];
    }

    // epilogue 2: r = w*64+i*16+quad*4+reg, f = j*16+frow (32B runs)
    #pragma unroll
    for (int i = 0; i < 4; ++i)
        #pragma unroll
        for (int r = 0; r < 4; ++r) {
            int rg = w * 64 + i * 16 + quad * 4 + r;
            ushort* Zr = Z + (size_t)((b << 8) + rg) * FsN + f0;
            #pragma unroll
            for (int j = 0; j < 4; ++j)
                Zr[j * 16 + frow] = f2bf(fmaxf(acc[i][j][r], 0.f));
        }
}

// ---------------- L5 fused: gemm N=2 (+bias) -> spmm(F=2, dense Sd) + relu ----------------
// block = batch b; y[256][2] in LDS; out compact [B*255, 2] f32.
__global__ __launch_bounds__(256) void l5_fused(const ushort* __restrict__ X,
                                                const float* __restrict__ Sd2,
                                                const float* __restrict__ Wd2,
                                                const float* __restrict__ bd2,
                                                float* __restrict__ out) {
    __shared__ float ysh[512];
    int b = blockIdx.x, t = threadIdx.x;
    // phase A: y[t] = X[b,t,:] @ Wd2 + bd2  (row 255 of X is zero -> y=bias, unused)
    const uint4* Xr = (const uint4*)(X + ((size_t)((b << 8) + t)) * 448);
    const float4* Wp = (const float4*)Wd2;   // float4 j covers k=2j,2j+1: {W[2j][0],W[2j][1],W[2j+1][0],W[2j+1][1]}
    float a0 = bd2[0], a1 = bd2[1];
    for (int i = 0; i < 50; ++i) {           // 50 uint4 = 400 bf16
        uint4 p = Xr[i];
        uint pv[4] = {p.x, p.y, p.z, p.w};
        #pragma unroll
        for (int q = 0; q < 4; ++q) {
            float x0 = bf2f((ushort)(pv[q] & 0xffffu));
            float x1 = bf2f((ushort)(pv[q] >> 16));
            float4 w = Wp[i * 4 + q];
            a0 = fmaf(x0, w.x, a0); a1 = fmaf(x0, w.y, a1);
            a0 = fmaf(x1, w.z, a0); a1 = fmaf(x1, w.w, a1);
        }
    }
    ysh[t * 2] = a0; ysh[t * 2 + 1] = a1;
    __syncthreads();
    // phase B: dense spmm + relu (Sd col 255 is zero)
    if (t < NN) {
        const float4* Sr = (const float4*)(Sd2 + (size_t)t * 256);
        float s0 = 0.f, s1 = 0.f;
        #pragma unroll 8
        for (int c4 = 0; c4 < 64; ++c4) {
            float4 v = Sr[c4];
            const float2* yp = (const float2*)&ysh[c4 * 8];
            float2 y0 = yp[0], y1 = yp[1], y2 = yp[2], y3 = yp[3];
            s0 = fmaf(v.x, y0.x, s0); s1 = fmaf(v.x, y0.y, s1);
            s0 = fmaf(v.y, y1.x, s0); s1 = fmaf(v.y, y1.y, s1);
            s0 = fmaf(v.z, y2.x, s0); s1 = fmaf(v.z, y2.y, s1);
            s0 = fmaf(v.w, y3.x, s0); s1 = fmaf(v.w, y3.y, s1);
        }
        out[((size_t)b * NN + t) * 2]     = fmaxf(s0, 0.f);
        out[((size_t)b * NN + t) * 2 + 1] = fmaxf(s1, 0.f);
    }
}

extern "C" void kernel_launch(void* const* d_in, const int* in_sizes, int n_in,
                              void* d_out, int out_size, void* d_ws, size_t ws_size,
                              hipStream_t stream) {
    const float* H = (const float*)d_in[0];
    const int*   g_rows[4] = {(const int*)d_in[1], (const int*)d_in[4], (const int*)d_in[7], (const int*)d_in[10]};
    const int*   g_cols[4] = {(const int*)d_in[2], (const int*)d_in[5], (const int*)d_in[8], (const int*)d_in[11]};
    const float* g_vals[4] = {(const float*)d_in[3], (const float*)d_in[6], (const float*)d_in[9], (const float*)d_in[12]};
    const float* W0  = (const float*)d_in[13]; const float* b0  = (const float*)d_in[14];
    const float* W1  = (const float*)d_in[15]; const float* b1  = (const float*)d_in[16];
    const float* W2  = (const float*)d_in[17]; const float* b2  = (const float*)d_in[18];
    const float* Wd0 = (const float*)d_in[19]; const float* bd0 = (const float*)d_in[20];
    const float* Wd1 = (const float*)d_in[21]; const float* bd1 = (const float*)d_in[22];
    const float* Wd2 = (const float*)d_in[23]; const float* bd2 = (const float*)d_in[24];
    float* out = (float*)d_out;

    const int nnz = in_sizes[1];
    const int B   = in_sizes[0] / (NN * 2);   // 256
    const int Mp  = B * 256;                  // 65536 (padded)

    // ---- workspace (ushort units) ----
    ushort* bufA = (ushort*)d_ws;                    // N-layout [Mp, <=448]
    ushort* bufB = bufA + (size_t)Mp * 448;          // N-layout [Mp, <=320]
    ushort* Wt1 = bufB + (size_t)Mp * 320;           // [320,416]
    ushort* Wt2 = Wt1 + 320 * 416;                   // [128,320]
    ushort* Wt3 = Wt2 + 128 * 320;                   // [320,128]
    ushort* Wt4 = Wt3 + 320 * 128;                   // [448,320]
    ushort* Sb  = Wt4 + 448 * 320;                   // 4 x [256,256] bf16
    // contiguous zero region: rs | Sd
    float*  rs  = (float*)(Sb + 4 * 65536);          // 4*256
    float*  Sd  = rs + 4 * 256;                      // 4*65536
    const int ZN = 4 * 256 + 4 * 65536;              // floats to zero

    // setup: 3 launches
    zero_k<<<(ZN + 255) / 256, 256, 0, stream>>>((int*)rs, ZN);
    edge_k<<<dim3((nnz + 255) / 256, 4), 256, 0, stream>>>(
        g_rows[0], g_cols[0], g_vals[0], g_rows[1], g_cols[1], g_vals[1],
        g_rows[2], g_cols[2], g_vals[2], g_rows[3], g_cols[3], g_vals[3],
        Sd, rs, nnz);
    conv_k<<<(620544 + 255) / 256, 256, 0, stream>>>(Sd, Sb, W1, Wt1, W2, Wt2, Wd0, Wt3, Wd1, Wt4);

    // L0: [2->400] g0, commuted spmm-first, fused.  H -> bufA[Mp,416]
    l0_fused<<<B, 256, 0, stream>>>(H, Sd + 0 * 65536, W0, b0, rs + 0, bufA);

    // L1: [400->300] g0.  bufA(K416) -> bufB(FsN 320), 5 f-tiles
    fused_layer<<<B * 5, 256, 0, stream>>>(bufA, Wt1, Sb + 0 * 65536, b1, bufB, 416, 300, 320, 5);
    // L2: [300->100] g1.  bufB(K320) -> bufA(FsN 128), 2 f-tiles
    fused_layer<<<B * 2, 256, 0, stream>>>(bufB, Wt2, Sb + 1 * 65536, b2, bufA, 320, 100, 128, 2);
    // L3: [100->300] g3.  bufA(K128) -> bufB(FsN 320), 5 f-tiles
    fused_layer<<<B * 5, 256, 0, stream>>>(bufA, Wt3, Sb + 3 * 65536, bd0, bufB, 128, 300, 320, 5);
    // L4: [300->400] g2.  bufB(K320) -> bufA(FsN 448), 7 f-tiles
    fused_layer<<<B * 7, 256, 0, stream>>>(bufB, Wt4, Sb + 2 * 65536, bd1, bufA, 320, 400, 448, 7);

    // L5: [400->2] g2, fused.  bufA(stride 448, K=400) -> out[B*255,2]
    l5_fused<<<B, 256, 0, stream>>>(bufA, Sd + 2 * 65536, Wd2, bd2, out);
}

// Round 16
// 367.199 us; speedup vs baseline: 1.1695x; 1.0390x over previous
//
#include <hip/hip_runtime.h>
#include <hip/hip_bf16.h>

// 6 layers of relu(spmm(graph, x@W+b)), B=256, NN=255 nodes.
// R15 = R14 + phase-1 MFMA operand swap (A=X, B=Wt) in fused_layer:
// D's quad-indexed m-dim now runs along c, so epilogue-1 writes 4 consecutive
// c per fragment => 16 aligned ds_write_b64 per lane instead of 64 ds_write_u16
// (which all landed in a 16-bank half). Ys layout + phase 2 unchanged
// (rotation invariant slot=(gc+(f>>2)&3)&3 preserved). Rest identical to R14.

#define NN 255
#define YCH 2048           // ushorts per Y k-chunk: 64 rows * 32

typedef __attribute__((ext_vector_type(8))) short short8;
typedef __attribute__((ext_vector_type(4))) float floatx4;

__device__ __forceinline__ float bf2f(ushort u) {
    union { uint u; float f; } c; c.u = ((uint)u) << 16; return c.f;
}
__device__ __forceinline__ ushort f2bf(float f) {
    union { float f; uint u; } c; c.f = f;
    uint u = c.u + 0x7fff + ((c.u >> 16) & 1);
    return (ushort)(u >> 16);
}
__device__ __forceinline__ short8 u4_frag(uint4 v) {
    union { uint4 u; short8 s; } c; c.u = v; return c.s;
}

// ---------------- graph preprocessing ----------------
__global__ void zero_k(int* p, int n) {
    int i = blockIdx.x * blockDim.x + threadIdx.x;
    if (i < n) p[i] = 0;
}

// per-edge: dense-S scatter + rowsum (f32 atomics)
__global__ void edge_k(const int* __restrict__ r0, const int* __restrict__ c0, const float* __restrict__ v0,
                       const int* __restrict__ r1, const int* __restrict__ c1, const float* __restrict__ v1,
                       const int* __restrict__ r2, const int* __restrict__ c2, const float* __restrict__ v2,
                       const int* __restrict__ r3, const int* __restrict__ c3, const float* __restrict__ v3,
                       float* Sd, float* rs, int nnz) {
    int gi = blockIdx.y;
    int e = blockIdx.x * blockDim.x + threadIdx.x;
    if (e >= nnz) return;
    const int* rr = gi == 0 ? r0 : gi == 1 ? r1 : gi == 2 ? r2 : r3;
    const int* cc = gi == 0 ? c0 : gi == 1 ? c1 : gi == 2 ? c2 : c3;
    const float* vv = gi == 0 ? v0 : gi == 1 ? v1 : gi == 2 ? v2 : v3;
    int r = rr[e], c = cc[e];
    float v = vv[e];
    atomicAdd(&Sd[gi * 65536 + r * 256 + c], v);
    atomicAdd(&rs[gi * 256 + r], v);
}

// merged converts: Sd->Sb (bf16) then 4 weight transposes (ladder on idx)
__device__ __forceinline__ void wpiece(const float* __restrict__ W, ushort* __restrict__ Wt,
                                       int K, int N, int Kpad, int idx) {
    int n = idx / Kpad, k = idx - n * Kpad;
    float v = (n < N && k < K) ? W[(size_t)k * N + n] : 0.f;
    Wt[idx] = f2bf(v);
}

__global__ void conv_k(const float* __restrict__ Sd, ushort* __restrict__ Sb,
                       const float* __restrict__ W1, ushort* __restrict__ Wt1,
                       const float* __restrict__ W2, ushort* __restrict__ Wt2,
                       const float* __restrict__ W3, ushort* __restrict__ Wt3,
                       const float* __restrict__ W4, ushort* __restrict__ Wt4) {
    int idx = blockIdx.x * blockDim.x + threadIdx.x;
    if (idx < 262144) { Sb[idx] = f2bf(Sd[idx]); return; }
    idx -= 262144;
    if (idx < 133120) { wpiece(W1, Wt1, 400, 300, 416, idx); return; }
    idx -= 133120;
    if (idx < 40960)  { wpiece(W2, Wt2, 300, 100, 320, idx); return; }
    idx -= 40960;
    if (idx < 40960)  { wpiece(W3, Wt3, 100, 300, 128, idx); return; }
    idx -= 40960;
    if (idx < 143360) { wpiece(W4, Wt4, 300, 400, 320, idx); }
}

// ---------------- L0 fused: spmm(F=2, dense Sd, f32) -> gemm K=2 + relu ----------------
__global__ __launch_bounds__(256) void l0_fused(const float* __restrict__ H,
                                                const float* __restrict__ Sd0,
                                                const float* __restrict__ W0,
                                                const float* __restrict__ b0,
                                                const float* __restrict__ rs0,
                                                ushort* __restrict__ Y) {
    __shared__ float hsh[512];      // H_b [256][2], slot 255 = 0
    __shared__ float ssh[512];      // spmm result [256][2]
    int b = blockIdx.x, t = threadIdx.x;
    if (t < NN) {
        hsh[t * 2]     = H[((size_t)b * NN + t) * 2];
        hsh[t * 2 + 1] = H[((size_t)b * NN + t) * 2 + 1];
    } else {
        hsh[t * 2] = 0.f; hsh[t * 2 + 1] = 0.f;
    }
    __syncthreads();
    const float4* Sr = (const float4*)(Sd0 + (size_t)t * 256);
    float s0 = 0.f, s1 = 0.f;
    #pragma unroll 8
    for (int c4 = 0; c4 < 64; ++c4) {
        float4 v = Sr[c4];
        const float2* hp = (const float2*)&hsh[c4 * 8];
        float2 h0 = hp[0], h1 = hp[1], h2 = hp[2], h3 = hp[3];
        s0 = fmaf(v.x, h0.x, s0); s1 = fmaf(v.x, h0.y, s1);
        s0 = fmaf(v.y, h1.x, s0); s1 = fmaf(v.y, h1.y, s1);
        s0 = fmaf(v.z, h2.x, s0); s1 = fmaf(v.z, h2.y, s1);
        s0 = fmaf(v.w, h3.x, s0); s1 = fmaf(v.w, h3.y, s1);
    }
    ssh[t * 2] = s0; ssh[t * 2 + 1] = s1;
    __syncthreads();
    uint* out = (uint*)(Y + (((size_t)b) << 8) * 416);
    for (int i = 0; i < 200; ++i) {
        int idx = i * 256 + t;
        int m = idx / 200, n2 = idx - m * 200;
        int n = n2 * 2;
        float x0 = ssh[m * 2], x1 = ssh[m * 2 + 1];
        float rsm = rs0[m];
        float y0 = fmaf(x0, W0[n],     fmaf(x1, W0[400 + n],     rsm * b0[n]));
        float y1 = fmaf(x0, W0[n + 1], fmaf(x1, W0[400 + n + 1], rsm * b0[n + 1]));
        out[(size_t)m * 208 + n2] =
            (uint)f2bf(fmaxf(y0, 0.f)) | ((uint)f2bf(fmaxf(y1, 0.f)) << 16);
    }
}

// =======================================================================
// Fused layer: block = (batch b, 64-feature tile ft).
//   phase 1: Y[64f,256c] = Wt_tile @ X_b^T + bias  (A=X, B=Wt; staged in LDS,
//            2 barriers/k-step, staging loads software-pipelined 1 step ahead)
//   phase 2: Z[256r,64f] = relu(S @ Y)             (S from L2 double-buffered, Y from LDS)
// LDS layout (rotation): row stride 32 ushorts (64B); 16B granule g of row r
// lives at position (g + (r>>2))&3. All frag ops are aligned b128/b64.
// =======================================================================
__global__ __launch_bounds__(256, 3) void fused_layer(const ushort* __restrict__ X,
                                                      const ushort* __restrict__ Wt,
                                                      const ushort* __restrict__ Sg,
                                                      const float* __restrict__ bias,
                                                      ushort* __restrict__ Z,
                                                      int Kpad, int Nfeat, int FsN,
                                                      int nft) {
    __shared__ ushort smem[8 * YCH];     // 32768 B total -> 5 blocks/CU
    ushort* As = smem;                   // [64][32]  phase-1 Wt staging
    ushort* Bs = smem + 64 * 32;         // [256][32] phase-1 X staging
    ushort* Ys = smem;                   // overlay: 8 chunks of [64][32]

    int li = blockIdx.x;
    int x = li & 7, rr = li >> 3;
    int ft = rr % nft, b = (rr / nft) * 8 + x;
    int f0 = ft * 64;

    int t = threadIdx.x;
    int w = t >> 6, lane = t & 63;
    int frow = lane & 15, quad = lane >> 4;
    int rot = ((quad + (frow >> 2)) & 3) * 8;   // frag-read granule offset (ushorts)

    // ---------------- phase 1 ----------------
    const ushort* Xb = X + (((size_t)b) << 8) * Kpad;
    const ushort* Apt = Wt + (size_t)(f0 + (t >> 2)) * Kpad + ((t & 3) * 8);
    const ushort* Bpt = Xb + (size_t)t * Kpad;
    ushort* AsW = &As[(t >> 2) * 32 + (((t & 3) + ((t >> 4) & 3)) & 3) * 8];
    ushort* BsW = &Bs[t * 32];
    int brot = (t >> 2) & 3;

    floatx4 acc[4][4];   // acc[i][j]: i = c-tile (A=X rows), j = f-tile (B=Wt rows)
    #pragma unroll
    for (int i = 0; i < 4; ++i)
        #pragma unroll
        for (int j = 0; j < 4; ++j) acc[i][j] = (floatx4)0.f;

    const ushort* Ab = &As[frow * 32 + rot];              // Wt frag base
    const ushort* Bb = &Bs[(w * 64 + frow) * 32 + rot];   // X frag base

    int nk1 = Kpad >> 5;
    uint4 pa  = *(const uint4*)(Apt);
    uint4 pb0 = *(const uint4*)(Bpt);
    uint4 pb1 = *(const uint4*)(Bpt + 8);
    uint4 pb2 = *(const uint4*)(Bpt + 16);
    uint4 pb3 = *(const uint4*)(Bpt + 24);
    Apt += 32; Bpt += 32;

    for (int ks = 0; ks < nk1; ++ks) {
        __syncthreads();                 // prev iter's frag reads done
        *(uint4*)AsW = pa;
        *(uint4*)(BsW + (((0 + brot) & 3) * 8)) = pb0;
        *(uint4*)(BsW + (((1 + brot) & 3) * 8)) = pb1;
        *(uint4*)(BsW + (((2 + brot) & 3) * 8)) = pb2;
        *(uint4*)(BsW + (((3 + brot) & 3) * 8)) = pb3;
        __syncthreads();
        if (ks + 1 < nk1) {              // prefetch chunk ks+1: in flight across MFMAs
            pa  = *(const uint4*)(Apt);
            pb0 = *(const uint4*)(Bpt);
            pb1 = *(const uint4*)(Bpt + 8);
            pb2 = *(const uint4*)(Bpt + 16);
            pb3 = *(const uint4*)(Bpt + 24);
            Apt += 32; Bpt += 32;
        }
        short8 xf[4], wf[4];
        #pragma unroll
        for (int i = 0; i < 4; ++i) {
            xf[i] = u4_frag(*(const uint4*)(Bb + i * 16 * 32));   // A operand: X rows
            wf[i] = u4_frag(*(const uint4*)(Ab + i * 16 * 32));   // B operand: Wt rows
        }
        #pragma unroll
        for (int i = 0; i < 4; ++i)
            #pragma unroll
            for (int j = 0; j < 4; ++j)
                acc[i][j] = __builtin_amdgcn_mfma_f32_16x16x32_bf16(xf[i], wf[j], acc[i][j], 0, 0, 0);
    }

    // issue phase-2 ks=0 S loads NOW: latency hides behind the epilogue barrier
    const ushort* Sp = Sg + (size_t)(w * 64 + frow) * 256 + quad * 8;
    uint4 ps[4];
    #pragma unroll
    for (int i = 0; i < 4; ++i) ps[i] = *(const uint4*)(Sp + i * 4096);

    // epilogue 1 -> Ys: c = w*64+i*16+quad*4+r (4 consecutive -> b64 write),
    // f = j*16+frow. Rotation key K(f)=(f>>2)&3 = (frow>>2)&3 (j*4 == 0 mod 4).
    __syncthreads();
    #pragma unroll
    for (int j = 0; j < 4; ++j) {
        int f = j * 16 + frow;
        float bv = (f0 + f < Nfeat) ? bias[f0 + f] : 0.f;
        #pragma unroll
        for (int i = 0; i < 4; ++i) {
            int chunk = 2 * w + (i >> 1);
            int gc = 2 * (i & 1) + (quad >> 1);
            int base = chunk * YCH + f * 32 + (((gc + (frow >> 2)) & 3) * 8) + (quad & 1) * 4;
            uint lo = (uint)f2bf(acc[i][j][0] + bv) | ((uint)f2bf(acc[i][j][1] + bv) << 16);
            uint hi = (uint)f2bf(acc[i][j][2] + bv) | ((uint)f2bf(acc[i][j][3] + bv) << 16);
            *(uint2*)(&Ys[base]) = make_uint2(lo, hi);
        }
    }
    __syncthreads();

    // ---------------- phase 2 (no barriers, S double-buffered) ----------------
    #pragma unroll
    for (int i = 0; i < 4; ++i)
        #pragma unroll
        for (int j = 0; j < 4; ++j) acc[i][j] = (floatx4)0.f;

    for (int ks = 0; ks < 8; ++ks) {
        uint4 pn[4];
        if (ks < 7) {
            #pragma unroll
            for (int i = 0; i < 4; ++i)
                pn[i] = *(const uint4*)(Sp + i * 4096 + (ks + 1) * 32);
        }
        short8 bf[4];
        #pragma unroll
        for (int j = 0; j < 4; ++j)
            bf[j] = u4_frag(*(const uint4*)(&Ys[ks * YCH + (j * 16 + frow) * 32 + rot]));
        #pragma unroll
        for (int i = 0; i < 4; ++i) {
            short8 af = u4_frag(ps[i]);
            #pragma unroll
            for (int j = 0; j < 4; ++j)
                acc[i][j] = __builtin_amdgcn_mfma_f32_16x16x32_bf16(af, bf[j], acc[i][j], 0, 0, 0);
        }
        #pragma unroll
        for (int i = 0; i < 4; ++i) ps[i] = pn[i];
    }

    // epilogue 2: r = w*64+i*16+quad*4+reg, f = j*16+frow (32B runs)
    #pragma unroll
    for (int i = 0; i < 4; ++i)
        #pragma unroll
        for (int r = 0; r < 4; ++r) {
            int rg = w * 64 + i * 16 + quad * 4 + r;
            ushort* Zr = Z + (size_t)((b << 8) + rg) * FsN + f0;
            #pragma unroll
            for (int j = 0; j < 4; ++j)
                Zr[j * 16 + frow] = f2bf(fmaxf(acc[i][j][r], 0.f));
        }
}

// ---------------- L5 fused: gemm N=2 (+bias) -> spmm(F=2, dense Sd) + relu ----------------
__global__ __launch_bounds__(256) void l5_fused(const ushort* __restrict__ X,
                                                const float* __restrict__ Sd2,
                                                const float* __restrict__ Wd2,
                                                const float* __restrict__ bd2,
                                                float* __restrict__ out) {
    __shared__ float ysh[512];
    int b = blockIdx.x, t = threadIdx.x;
    const uint4* Xr = (const uint4*)(X + ((size_t)((b << 8) + t)) * 448);
    const float4* Wp = (const float4*)Wd2;
    float a0 = bd2[0], a1 = bd2[1];
    for (int i = 0; i < 50; ++i) {
        uint4 p = Xr[i];
        uint pv[4] = {p.x, p.y, p.z, p.w};
        #pragma unroll
        for (int q = 0; q < 4; ++q) {
            float x0 = bf2f((ushort)(pv[q] & 0xffffu));
            float x1 = bf2f((ushort)(pv[q] >> 16));
            float4 w = Wp[i * 4 + q];
            a0 = fmaf(x0, w.x, a0); a1 = fmaf(x0, w.y, a1);
            a0 = fmaf(x1, w.z, a0); a1 = fmaf(x1, w.w, a1);
        }
    }
    ysh[t * 2] = a0; ysh[t * 2 + 1] = a1;
    __syncthreads();
    if (t < NN) {
        const float4* Sr = (const float4*)(Sd2 + (size_t)t * 256);
        float s0 = 0.f, s1 = 0.f;
        #pragma unroll 8
        for (int c4 = 0; c4 < 64; ++c4) {
            float4 v = Sr[c4];
            const float2* yp = (const float2*)&ysh[c4 * 8];
            float2 y0 = yp[0], y1 = yp[1], y2 = yp[2], y3 = yp[3];
            s0 = fmaf(v.x, y0.x, s0); s1 = fmaf(v.x, y0.y, s1);
            s0 = fmaf(v.y, y1.x, s0); s1 = fmaf(v.y, y1.y, s1);
            s0 = fmaf(v.z, y2.x, s0); s1 = fmaf(v.z, y2.y, s1);
            s0 = fmaf(v.w, y3.x, s0); s1 = fmaf(v.w, y3.y, s1);
        }
        out[((size_t)b * NN + t) * 2]     = fmaxf(s0, 0.f);
        out[((size_t)b * NN + t) * 2 + 1] = fmaxf(s1, 0.f);
    }
}

extern "C" void kernel_launch(void* const* d_in, const int* in_sizes, int n_in,
                              void* d_out, int out_size, void* d_ws, size_t ws_size,
                              hipStream_t stream) {
    const float* H = (const float*)d_in[0];
    const int*   g_rows[4] = {(const int*)d_in[1], (const int*)d_in[4], (const int*)d_in[7], (const int*)d_in[10]};
    const int*   g_cols[4] = {(const int*)d_in[2], (const int*)d_in[5], (const int*)d_in[8], (const int*)d_in[11]};
    const float* g_vals[4] = {(const float*)d_in[3], (const float*)d_in[6], (const float*)d_in[9], (const float*)d_in[12]};
    const float* W0  = (const float*)d_in[13]; const float* b0  = (const float*)d_in[14];
    const float* W1  = (const float*)d_in[15]; const float* b1  = (const float*)d_in[16];
    const float* W2  = (const float*)d_in[17]; const float* b2  = (const float*)d_in[18];
    const float* Wd0 = (const float*)d_in[19]; const float* bd0 = (const float*)d_in[20];
    const float* Wd1 = (const float*)d_in[21]; const float* bd1 = (const float*)d_in[22];
    const float* Wd2 = (const float*)d_in[23]; const float* bd2 = (const float*)d_in[24];
    float* out = (float*)d_out;

    const int nnz = in_sizes[1];
    const int B   = in_sizes[0] / (NN * 2);   // 256
    const int Mp  = B * 256;                  // 65536 (padded)

    // ---- workspace (ushort units) ----
    ushort* bufA = (ushort*)d_ws;                    // N-layout [Mp, <=448]
    ushort* bufB = bufA + (size_t)Mp * 448;          // N-layout [Mp, <=320]
    ushort* Wt1 = bufB + (size_t)Mp * 320;           // [320,416]
    ushort* Wt2 = Wt1 + 320 * 416;                   // [128,320]
    ushort* Wt3 = Wt2 + 128 * 320;                   // [320,128]
    ushort* Wt4 = Wt3 + 320 * 128;                   // [448,320]
    ushort* Sb  = Wt4 + 448 * 320;                   // 4 x [256,256] bf16
    float*  rs  = (float*)(Sb + 4 * 65536);          // 4*256
    float*  Sd  = rs + 4 * 256;                      // 4*65536
    const int ZN = 4 * 256 + 4 * 65536;

    // setup: 3 launches
    zero_k<<<(ZN + 255) / 256, 256, 0, stream>>>((int*)rs, ZN);
    edge_k<<<dim3((nnz + 255) / 256, 4), 256, 0, stream>>>(
        g_rows[0], g_cols[0], g_vals[0], g_rows[1], g_cols[1], g_vals[1],
        g_rows[2], g_cols[2], g_vals[2], g_rows[3], g_cols[3], g_vals[3],
        Sd, rs, nnz);
    conv_k<<<(620544 + 255) / 256, 256, 0, stream>>>(Sd, Sb, W1, Wt1, W2, Wt2, Wd0, Wt3, Wd1, Wt4);

    // L0: [2->400] g0, commuted spmm-first, fused.  H -> bufA[Mp,416]
    l0_fused<<<B, 256, 0, stream>>>(H, Sd + 0 * 65536, W0, b0, rs + 0, bufA);

    // L1: [400->300] g0.  bufA(K416) -> bufB(FsN 320), 5 f-tiles
    fused_layer<<<B * 5, 256, 0, stream>>>(bufA, Wt1, Sb + 0 * 65536, b1, bufB, 416, 300, 320, 5);
    // L2: [300->100] g1.  bufB(K320) -> bufA(FsN 128), 2 f-tiles
    fused_layer<<<B * 2, 256, 0, stream>>>(bufB, Wt2, Sb + 1 * 65536, b2, bufA, 320, 100, 128, 2);
    // L3: [100->300] g3.  bufA(K128) -> bufB(FsN 320), 5 f-tiles
    fused_layer<<<B * 5, 256, 0, stream>>>(bufA, Wt3, Sb + 3 * 65536, bd0, bufB, 128, 300, 320, 5);
    // L4: [300->400] g2.  bufB(K320) -> bufA(FsN 448), 7 f-tiles
    fused_layer<<<B * 7, 256, 0, stream>>>(bufB, Wt4, Sb + 2 * 65536, bd1, bufA, 320, 400, 448, 7);

    // L5: [400->2] g2, fused.  bufA(stride 448, K=400) -> out[B*255,2]
    l5_fused<<<B, 256, 0, stream>>>(bufA, Sd + 2 * 65536, Wd2, bd2, out);
}